// Round 1
// baseline (10668.301 us; speedup 1.0000x reference)
//
#include <hip/hip_runtime.h>

// G4GCN: 4-layer linear bipartite GNN (clauses <-> variables), feature dim 2.
//
// Per layer l:
//   Sv_pos[v] = sum_{pos edges (c,v)} inv_c[c]*xc[c]      (and same for neg)
//   Sc_pos[c] = sum_{pos edges (c,v)} inv_v[v]*xv[v]
//   v_pos = inv_v[v]*Sv_pos[v] + cnt_v_pos[v]*xv[v]       (the "+x_trg" term telescopes)
//   xv' = [v_pos, v_neg, xv] @ Wv[l] + bv[l]   (6->2), same for clauses.
//
// One edge pass per polarity per layer does BOTH directions (4 float atomics/edge).
// Edge counts (cnt_*) are layer-independent: one extra pass up front.

static inline int cdiv(long long a, int b) { return (int)((a + b - 1) / b); }

__global__ void init_nodes(const float* __restrict__ x, const float* __restrict__ deg,
                           const float* __restrict__ W0, const float* __restrict__ b0,
                           float2* __restrict__ xf, float* __restrict__ inv, int n) {
    int i = blockIdx.x * blockDim.x + threadIdx.x;
    if (i >= n) return;
    float xi = x[i];
    xf[i] = make_float2(fmaf(xi, W0[0], b0[0]), fmaf(xi, W0[1], b0[1]));
    float d = deg[i];
    inv[i] = (d > 0.0f) ? (1.0f / sqrtf(d)) : 0.0f;
}

__global__ void count_edges(const int* __restrict__ src, const int* __restrict__ trg,
                            float* __restrict__ cnt_src, float* __restrict__ cnt_trg, int e) {
    int i = blockIdx.x * blockDim.x + threadIdx.x;
    if (i >= e) return;
    atomicAdd(&cnt_src[src[i]], 1.0f);
    atomicAdd(&cnt_trg[trg[i]], 1.0f);
}

// One pass over an edge list: scatter both directions.
__global__ void edge_pass(const int* __restrict__ src, const int* __restrict__ trg,
                          const float2* __restrict__ xc, const float2* __restrict__ xv,
                          const float* __restrict__ inv_c, const float* __restrict__ inv_v,
                          float2* __restrict__ Sv, float2* __restrict__ Sc, int e) {
    int i = blockIdx.x * blockDim.x + threadIdx.x;
    if (i >= e) return;
    int c = src[i];
    int v = trg[i];
    float ic = inv_c[c], iv = inv_v[v];
    float2 a = xc[c];
    float2 b = xv[v];
    atomicAdd(&Sv[v].x, a.x * ic);
    atomicAdd(&Sv[v].y, a.y * ic);
    atomicAdd(&Sc[c].x, b.x * iv);
    atomicAdd(&Sc[c].y, b.y * iv);
}

// x' = [inv*Sp + cp*x, inv*Sn + cn*x, x] @ W(6x2) + b, in place.
__global__ void node_update(float2* __restrict__ x, const float2* __restrict__ Sp,
                            const float2* __restrict__ Sn, const float* __restrict__ inv,
                            const float* __restrict__ cp, const float* __restrict__ cn,
                            const float* __restrict__ W, const float* __restrict__ b, int n) {
    int i = blockIdx.x * blockDim.x + threadIdx.x;
    if (i >= n) return;
    float2 xi = x[i];
    float ii = inv[i];
    float2 sp = Sp[i], sn = Sn[i];
    float cpi = cp[i], cni = cn[i];
    float m0 = fmaf(ii, sp.x, cpi * xi.x);
    float m1 = fmaf(ii, sp.y, cpi * xi.y);
    float m2 = fmaf(ii, sn.x, cni * xi.x);
    float m3 = fmaf(ii, sn.y, cni * xi.y);
    // W row-major [6][2]
    float o0 = b[0] + m0 * W[0] + m1 * W[2] + m2 * W[4] + m3 * W[6] + xi.x * W[8] + xi.y * W[10];
    float o1 = b[1] + m0 * W[1] + m1 * W[3] + m2 * W[5] + m3 * W[7] + xi.x * W[9] + xi.y * W[11];
    x[i] = make_float2(o0, o1);
}

extern "C" void kernel_launch(void* const* d_in, const int* in_sizes, int n_in,
                              void* d_out, int out_size, void* d_ws, size_t ws_size,
                              hipStream_t stream) {
    const float* x_clause   = (const float*)d_in[0];
    const float* x_variable = (const float*)d_in[1];
    const float* deg_clause = (const float*)d_in[2];
    const float* deg_var    = (const float*)d_in[3];
    const int*   pos_src    = (const int*)d_in[4];
    const int*   pos_trg    = (const int*)d_in[5];
    const int*   neg_src    = (const int*)d_in[6];
    const int*   neg_trg    = (const int*)d_in[7];
    const float* W0c        = (const float*)d_in[8];
    const float* b0c        = (const float*)d_in[9];
    const float* W0v        = (const float*)d_in[10];
    const float* b0v        = (const float*)d_in[11];
    const float* Wc         = (const float*)d_in[12];
    const float* bc         = (const float*)d_in[13];
    const float* Wv         = (const float*)d_in[14];
    const float* bv         = (const float*)d_in[15];

    const int nc = in_sizes[0];
    const int nv = in_sizes[1];
    const int e  = in_sizes[4];

    // Workspace layout (float2 arrays first, then floats).
    char* p = (char*)d_ws;
    float2* Sv_pos = (float2*)p; p += (size_t)nv * sizeof(float2);
    float2* Sv_neg = (float2*)p; p += (size_t)nv * sizeof(float2);
    float2* Sc_pos = (float2*)p; p += (size_t)nc * sizeof(float2);
    float2* Sc_neg = (float2*)p; p += (size_t)nc * sizeof(float2);
    const size_t s_bytes = (size_t)(2 * nv + 2 * nc) * sizeof(float2);
    float2* xc = (float2*)p; p += (size_t)nc * sizeof(float2);
    float* inv_c = (float*)p; p += (size_t)nc * sizeof(float);
    float* inv_v = (float*)p; p += (size_t)nv * sizeof(float);
    float* cntc_pos = (float*)p; p += (size_t)nc * sizeof(float);
    float* cntc_neg = (float*)p; p += (size_t)nc * sizeof(float);
    float* cntv_pos = (float*)p; p += (size_t)nv * sizeof(float);
    float* cntv_neg = (float*)p; p += (size_t)nv * sizeof(float);
    const size_t cnt_bytes = (size_t)(2 * nc + 2 * nv) * sizeof(float);

    float2* xv = (float2*)d_out;  // xv lives in d_out throughout; final state IS the output.

    const int B = 256;

    hipMemsetAsync(Sv_pos, 0, s_bytes, stream);      // S block is contiguous
    hipMemsetAsync(cntc_pos, 0, cnt_bytes, stream);  // cnt block is contiguous

    init_nodes<<<cdiv(nc, B), B, 0, stream>>>(x_clause, deg_clause, W0c, b0c, xc, inv_c, nc);
    init_nodes<<<cdiv(nv, B), B, 0, stream>>>(x_variable, deg_var, W0v, b0v, xv, inv_v, nv);

    count_edges<<<cdiv(e, B), B, 0, stream>>>(pos_src, pos_trg, cntc_pos, cntv_pos, e);
    count_edges<<<cdiv(e, B), B, 0, stream>>>(neg_src, neg_trg, cntc_neg, cntv_neg, e);

    for (int l = 0; l < 4; ++l) {
        edge_pass<<<cdiv(e, B), B, 0, stream>>>(pos_src, pos_trg, xc, xv, inv_c, inv_v,
                                                Sv_pos, Sc_pos, e);
        edge_pass<<<cdiv(e, B), B, 0, stream>>>(neg_src, neg_trg, xc, xv, inv_c, inv_v,
                                                Sv_neg, Sc_neg, e);
        node_update<<<cdiv(nv, B), B, 0, stream>>>(xv, Sv_pos, Sv_neg, inv_v,
                                                   cntv_pos, cntv_neg, Wv + l * 12, bv + l * 2, nv);
        node_update<<<cdiv(nc, B), B, 0, stream>>>(xc, Sc_pos, Sc_neg, inv_c,
                                                   cntc_pos, cntc_neg, Wc + l * 12, bc + l * 2, nc);
        if (l < 3) hipMemsetAsync(Sv_pos, 0, s_bytes, stream);
    }
}

// Round 2
// 2428.090 us; speedup vs baseline: 4.3937x; 4.3937x over previous
//
#include <hip/hip_runtime.h>

// G4GCN: 4-layer linear bipartite GNN (clauses <-> variables), feature dim 2.
//
// Strategy: global float atomics cost ~64B coherent RMW each (measured: 2 GB
// EA traffic per edge pass). Instead, bucket each edge view ONCE by its target
// (deterministic counting partition), then per layer accumulate messages in
// LDS with a fused node update. No global atomics anywhere.
//
// Bucketing: variables in ranges of 256 (loc=8 bits, src clause id 21 bits ->
// 29-bit packed entry), clauses in ranges of 1024 (loc=10 bits, src variable
// id 19 bits -> 29 bits). NB = ceil(500k/256) = ceil(2M/1024) = 1954 buckets.

#define GA 512  // blocks for build passes (hist/scatter)

static inline int cdiv_h(long long a, long long b) { return (int)((a + b - 1) / b); }

// ---------------- build: counting partition ----------------

__global__ void hist_kernel(const int* __restrict__ key, int e, int chunk, int shift,
                            int nb, unsigned* __restrict__ hist /*[nb][GA]*/) {
    extern __shared__ unsigned h[];
    int blk = blockIdx.x, tid = threadIdx.x;
    for (int i = tid; i < nb; i += blockDim.x) h[i] = 0u;
    __syncthreads();
    int s = blk * chunk, epos = min(e, s + chunk);
    for (int i = s + tid; i < epos; i += blockDim.x)
        atomicAdd(&h[key[i] >> shift], 1u);
    __syncthreads();
    for (int i = tid; i < nb; i += blockDim.x) hist[(size_t)i * GA + blk] = h[i];
}

// one block per bucket row; exclusive scan of hist[b][0..GA) -> rowscan, total -> row_total[b]
__global__ void rowscan_kernel(const unsigned* __restrict__ hist, unsigned* __restrict__ rowscan,
                               unsigned* __restrict__ row_total) {
    __shared__ unsigned a[GA];
    __shared__ unsigned ts[256];
    int b = blockIdx.x, t = threadIdx.x;
    a[t] = hist[(size_t)b * GA + t];
    a[t + 256] = hist[(size_t)b * GA + t + 256];
    __syncthreads();
    unsigned a0 = a[2 * t], a1 = a[2 * t + 1];
    unsigned sum = a0 + a1;
    ts[t] = sum;
    __syncthreads();
    for (int off = 1; off < 256; off <<= 1) {
        unsigned v = (t >= off) ? ts[t - off] : 0u;
        __syncthreads();
        ts[t] += v;
        __syncthreads();
    }
    unsigned base = ts[t] - sum;  // exclusive
    rowscan[(size_t)b * GA + 2 * t] = base;
    rowscan[(size_t)b * GA + 2 * t + 1] = base + a0;
    if (t == 255) row_total[b] = ts[255];
}

// single block, 1024 threads: exclusive scan of row_total[0..nb) -> base[0..nb]
__global__ void basescan_kernel(const unsigned* __restrict__ row_total,
                                unsigned* __restrict__ base, int nb) {
    __shared__ unsigned a[2048];
    __shared__ unsigned ts[1024];
    int t = threadIdx.x;
    a[t] = (t < nb) ? row_total[t] : 0u;
    a[t + 1024] = (t + 1024 < nb) ? row_total[t + 1024] : 0u;
    __syncthreads();
    unsigned a0 = a[2 * t], a1 = a[2 * t + 1];
    unsigned sum = a0 + a1;
    ts[t] = sum;
    __syncthreads();
    for (int off = 1; off < 1024; off <<= 1) {
        unsigned v = (t >= off) ? ts[t - off] : 0u;
        __syncthreads();
        ts[t] += v;
        __syncthreads();
    }
    unsigned b0 = ts[t] - sum;
    if (2 * t <= nb) base[2 * t] = b0;
    if (2 * t + 1 <= nb) base[2 * t + 1] = b0 + a0;
}

__global__ void scatter_kernel(const int* __restrict__ key, const int* __restrict__ payload,
                               int e, int chunk, int shift, int mask, int nb,
                               const unsigned* __restrict__ rowscan,
                               const unsigned* __restrict__ base,
                               unsigned* __restrict__ out) {
    extern __shared__ unsigned cur[];
    int blk = blockIdx.x, tid = threadIdx.x;
    for (int i = tid; i < nb; i += blockDim.x)
        cur[i] = base[i] + rowscan[(size_t)i * GA + blk];
    __syncthreads();
    int s = blk * chunk, epos = min(e, s + chunk);
    for (int i = s + tid; i < epos; i += blockDim.x) {
        int k = key[i];
        int b = k >> shift;
        unsigned p = atomicAdd(&cur[b], 1u);
        out[p] = ((unsigned)payload[i] << shift) | (unsigned)(k & mask);
    }
}

// ---------------- per-layer fused kernels ----------------

__global__ void init_nodes2(const float* __restrict__ x, const float* __restrict__ W0,
                            const float* __restrict__ b0, float2* __restrict__ xf, int n) {
    int i = blockIdx.x * blockDim.x + threadIdx.x;
    if (i >= n) return;
    float xi = x[i];
    xf[i] = make_float2(fmaf(xi, W0[0], b0[0]), fmaf(xi, W0[1], b0[1]));
}

// variable side: buckets of 256 nodes; one node per thread. writes xv_out (ping-pong)
__global__ __launch_bounds__(256) void v_layer_kernel(
    const unsigned* __restrict__ bkt_pos, const unsigned* __restrict__ base_pos,
    const unsigned* __restrict__ bkt_neg, const unsigned* __restrict__ base_neg,
    const float2* __restrict__ xc, const float* __restrict__ deg_c,
    const float2* __restrict__ xv_in, const float* __restrict__ deg_v,
    const float* __restrict__ W, const float* __restrict__ bias,
    float2* __restrict__ xv_out, int nv) {
    __shared__ float sx[2][256], sy[2][256], cnt[2][256];
    int b = blockIdx.x, t = threadIdx.x;
    sx[0][t] = 0.f; sx[1][t] = 0.f; sy[0][t] = 0.f; sy[1][t] = 0.f;
    cnt[0][t] = 0.f; cnt[1][t] = 0.f;
    __syncthreads();
    for (int pol = 0; pol < 2; ++pol) {
        const unsigned* bkt = pol ? bkt_neg : bkt_pos;
        const unsigned* bse = pol ? base_neg : base_pos;
        unsigned s = bse[b], epos = bse[b + 1];
        for (unsigned i = s + t; i < epos; i += 256) {
            unsigned u = bkt[i];
            int src = (int)(u >> 8);
            int loc = (int)(u & 255u);
            float d = deg_c[src];
            float ic = (d > 0.f) ? rsqrtf(d) : 0.f;
            float2 y = xc[src];
            atomicAdd(&sx[pol][loc], ic * y.x);
            atomicAdd(&sy[pol][loc], ic * y.y);
            atomicAdd(&cnt[pol][loc], 1.0f);
        }
    }
    __syncthreads();
    int node = b * 256 + t;
    if (node < nv) {
        float2 xi = xv_in[node];
        float dv = deg_v[node];
        float iv = (dv > 0.f) ? rsqrtf(dv) : 0.f;
        float m0 = fmaf(iv, sx[0][t], cnt[0][t] * xi.x);
        float m1 = fmaf(iv, sy[0][t], cnt[0][t] * xi.y);
        float m2 = fmaf(iv, sx[1][t], cnt[1][t] * xi.x);
        float m3 = fmaf(iv, sy[1][t], cnt[1][t] * xi.y);
        float o0 = bias[0] + m0 * W[0] + m1 * W[2] + m2 * W[4] + m3 * W[6] + xi.x * W[8] + xi.y * W[10];
        float o1 = bias[1] + m0 * W[1] + m1 * W[3] + m2 * W[5] + m3 * W[7] + xi.x * W[9] + xi.y * W[11];
        xv_out[node] = make_float2(o0, o1);
    }
}

// clause side: buckets of 1024 nodes; 4 nodes per thread. xc updated IN PLACE
// (each block reads/writes only its own contiguous clause range; messages gather xv_in).
__global__ __launch_bounds__(256) void c_layer_kernel(
    const unsigned* __restrict__ bkt_pos, const unsigned* __restrict__ base_pos,
    const unsigned* __restrict__ bkt_neg, const unsigned* __restrict__ base_neg,
    const float2* __restrict__ xv_in, const float* __restrict__ deg_v,
    float2* __restrict__ xc, const float* __restrict__ deg_c,
    const float* __restrict__ W, const float* __restrict__ bias, int nc) {
    __shared__ float sx[2][1024], sy[2][1024], cnt[2][1024];
    int b = blockIdx.x, t = threadIdx.x;
    for (int k = 0; k < 4; ++k) {
        int j = t + 256 * k;
        sx[0][j] = 0.f; sx[1][j] = 0.f; sy[0][j] = 0.f; sy[1][j] = 0.f;
        cnt[0][j] = 0.f; cnt[1][j] = 0.f;
    }
    __syncthreads();
    for (int pol = 0; pol < 2; ++pol) {
        const unsigned* bkt = pol ? bkt_neg : bkt_pos;
        const unsigned* bse = pol ? base_neg : base_pos;
        unsigned s = bse[b], epos = bse[b + 1];
        for (unsigned i = s + t; i < epos; i += 256) {
            unsigned u = bkt[i];
            int src = (int)(u >> 10);
            int loc = (int)(u & 1023u);
            float d = deg_v[src];
            float iv = (d > 0.f) ? rsqrtf(d) : 0.f;
            float2 y = xv_in[src];
            atomicAdd(&sx[pol][loc], iv * y.x);
            atomicAdd(&sy[pol][loc], iv * y.y);
            atomicAdd(&cnt[pol][loc], 1.0f);
        }
    }
    __syncthreads();
    for (int k = 0; k < 4; ++k) {
        int j = t + 256 * k;
        int node = b * 1024 + j;
        if (node < nc) {
            float2 xi = xc[node];
            float dc = deg_c[node];
            float ic = (dc > 0.f) ? rsqrtf(dc) : 0.f;
            float m0 = fmaf(ic, sx[0][j], cnt[0][j] * xi.x);
            float m1 = fmaf(ic, sy[0][j], cnt[0][j] * xi.y);
            float m2 = fmaf(ic, sx[1][j], cnt[1][j] * xi.x);
            float m3 = fmaf(ic, sy[1][j], cnt[1][j] * xi.y);
            float o0 = bias[0] + m0 * W[0] + m1 * W[2] + m2 * W[4] + m3 * W[6] + xi.x * W[8] + xi.y * W[10];
            float o1 = bias[1] + m0 * W[1] + m1 * W[3] + m2 * W[5] + m3 * W[7] + xi.x * W[9] + xi.y * W[11];
            xc[node] = make_float2(o0, o1);
        }
    }
}

// ---------------- fallback (round-0 atomic path) ----------------

__global__ void init_nodes(const float* __restrict__ x, const float* __restrict__ deg,
                           const float* __restrict__ W0, const float* __restrict__ b0,
                           float2* __restrict__ xf, float* __restrict__ inv, int n) {
    int i = blockIdx.x * blockDim.x + threadIdx.x;
    if (i >= n) return;
    float xi = x[i];
    xf[i] = make_float2(fmaf(xi, W0[0], b0[0]), fmaf(xi, W0[1], b0[1]));
    float d = deg[i];
    inv[i] = (d > 0.0f) ? (1.0f / sqrtf(d)) : 0.0f;
}

__global__ void count_edges(const int* __restrict__ src, const int* __restrict__ trg,
                            float* __restrict__ cnt_src, float* __restrict__ cnt_trg, int e) {
    int i = blockIdx.x * blockDim.x + threadIdx.x;
    if (i >= e) return;
    atomicAdd(&cnt_src[src[i]], 1.0f);
    atomicAdd(&cnt_trg[trg[i]], 1.0f);
}

__global__ void edge_pass(const int* __restrict__ src, const int* __restrict__ trg,
                          const float2* __restrict__ xc, const float2* __restrict__ xv,
                          const float* __restrict__ inv_c, const float* __restrict__ inv_v,
                          float2* __restrict__ Sv, float2* __restrict__ Sc, int e) {
    int i = blockIdx.x * blockDim.x + threadIdx.x;
    if (i >= e) return;
    int c = src[i];
    int v = trg[i];
    float ic = inv_c[c], iv = inv_v[v];
    float2 a = xc[c];
    float2 b = xv[v];
    atomicAdd(&Sv[v].x, a.x * ic);
    atomicAdd(&Sv[v].y, a.y * ic);
    atomicAdd(&Sc[c].x, b.x * iv);
    atomicAdd(&Sc[c].y, b.y * iv);
}

__global__ void node_update(float2* __restrict__ x, const float2* __restrict__ Sp,
                            const float2* __restrict__ Sn, const float* __restrict__ inv,
                            const float* __restrict__ cp, const float* __restrict__ cn,
                            const float* __restrict__ W, const float* __restrict__ b, int n) {
    int i = blockIdx.x * blockDim.x + threadIdx.x;
    if (i >= n) return;
    float2 xi = x[i];
    float ii = inv[i];
    float2 sp = Sp[i], sn = Sn[i];
    float cpi = cp[i], cni = cn[i];
    float m0 = fmaf(ii, sp.x, cpi * xi.x);
    float m1 = fmaf(ii, sp.y, cpi * xi.y);
    float m2 = fmaf(ii, sn.x, cni * xi.x);
    float m3 = fmaf(ii, sn.y, cni * xi.y);
    float o0 = b[0] + m0 * W[0] + m1 * W[2] + m2 * W[4] + m3 * W[6] + xi.x * W[8] + xi.y * W[10];
    float o1 = b[1] + m0 * W[1] + m1 * W[3] + m2 * W[5] + m3 * W[7] + xi.x * W[9] + xi.y * W[11];
    x[i] = make_float2(o0, o1);
}

// ---------------- launch ----------------

extern "C" void kernel_launch(void* const* d_in, const int* in_sizes, int n_in,
                              void* d_out, int out_size, void* d_ws, size_t ws_size,
                              hipStream_t stream) {
    const float* x_clause   = (const float*)d_in[0];
    const float* x_variable = (const float*)d_in[1];
    const float* deg_clause = (const float*)d_in[2];
    const float* deg_var    = (const float*)d_in[3];
    const int*   pos_src    = (const int*)d_in[4];
    const int*   pos_trg    = (const int*)d_in[5];
    const int*   neg_src    = (const int*)d_in[6];
    const int*   neg_trg    = (const int*)d_in[7];
    const float* W0c        = (const float*)d_in[8];
    const float* b0c        = (const float*)d_in[9];
    const float* W0v        = (const float*)d_in[10];
    const float* b0v        = (const float*)d_in[11];
    const float* Wc         = (const float*)d_in[12];
    const float* bc         = (const float*)d_in[13];
    const float* Wv         = (const float*)d_in[14];
    const float* bv         = (const float*)d_in[15];

    const int nc = in_sizes[0];
    const int nv = in_sizes[1];
    const int e  = in_sizes[4];
    const int B = 256;

    const int NBV = cdiv_h(nv, 256);   // variable buckets of 256
    const int NBC = cdiv_h(nc, 1024);  // clause buckets of 1024
    const int maxnb = NBV > NBC ? NBV : NBC;

    // workspace layout (new path)
    size_t off = 0;
    auto alloc = [&](size_t bytes) {
        void* p = (char*)d_ws + off;
        off += (bytes + 255) & ~(size_t)255;
        return p;
    };
    unsigned* bkt_vpos = (unsigned*)alloc((size_t)e * 4);
    unsigned* bkt_vneg = (unsigned*)alloc((size_t)e * 4);
    unsigned* bkt_cpos = (unsigned*)alloc((size_t)e * 4);
    unsigned* bkt_cneg = (unsigned*)alloc((size_t)e * 4);
    unsigned* hist     = (unsigned*)alloc((size_t)maxnb * GA * 4);
    unsigned* rowscan  = (unsigned*)alloc((size_t)maxnb * GA * 4);
    unsigned* row_tot  = (unsigned*)alloc((size_t)maxnb * 4);
    unsigned* base_vp  = (unsigned*)alloc((size_t)(NBV + 1) * 4);
    unsigned* base_vn  = (unsigned*)alloc((size_t)(NBV + 1) * 4);
    unsigned* base_cp  = (unsigned*)alloc((size_t)(NBC + 1) * 4);
    unsigned* base_cn  = (unsigned*)alloc((size_t)(NBC + 1) * 4);
    float2*   xc       = (float2*)alloc((size_t)nc * 8);
    float2*   xvB      = (float2*)alloc((size_t)nv * 8);
    const size_t required = off;

    if (required <= ws_size && NBV <= 2048 && NBC <= 2048) {
        const int chunk = cdiv_h(e, GA);
        // build the 4 bucketed views: (key=target, payload=source)
        struct { const int* key; const int* pay; int shift; int nb; unsigned* out; unsigned* base; } L[4] = {
            { pos_trg, pos_src,  8, NBV, bkt_vpos, base_vp },
            { neg_trg, neg_src,  8, NBV, bkt_vneg, base_vn },
            { pos_src, pos_trg, 10, NBC, bkt_cpos, base_cp },
            { neg_src, neg_trg, 10, NBC, bkt_cneg, base_cn },
        };
        for (int i = 0; i < 4; ++i) {
            size_t smem = (size_t)L[i].nb * 4;
            hist_kernel<<<GA, B, smem, stream>>>(L[i].key, e, chunk, L[i].shift, L[i].nb, hist);
            rowscan_kernel<<<L[i].nb, B, 0, stream>>>(hist, rowscan, row_tot);
            basescan_kernel<<<1, 1024, 0, stream>>>(row_tot, L[i].base, L[i].nb);
            scatter_kernel<<<GA, B, smem, stream>>>(L[i].key, L[i].pay, e, chunk, L[i].shift,
                                                    (1 << L[i].shift) - 1, L[i].nb,
                                                    rowscan, L[i].base, L[i].out);
        }

        float2* xvA = (float2*)d_out;  // layers: A->B->A->B->A, final in d_out
        init_nodes2<<<cdiv_h(nc, B), B, 0, stream>>>(x_clause, W0c, b0c, xc, nc);
        init_nodes2<<<cdiv_h(nv, B), B, 0, stream>>>(x_variable, W0v, b0v, xvA, nv);

        float2* cur = xvA;
        float2* nxt = xvB;
        for (int l = 0; l < 4; ++l) {
            v_layer_kernel<<<NBV, B, 0, stream>>>(bkt_vpos, base_vp, bkt_vneg, base_vn,
                                                  xc, deg_clause, cur, deg_var,
                                                  Wv + l * 12, bv + l * 2, nxt, nv);
            if (l < 3) {
                c_layer_kernel<<<NBC, B, 0, stream>>>(bkt_cpos, base_cp, bkt_cneg, base_cn,
                                                      cur, deg_var, xc, deg_clause,
                                                      Wc + l * 12, bc + l * 2, nc);
            }
            float2* tmp = cur; cur = nxt; nxt = tmp;
        }
        return;
    }

    // ---------------- fallback: round-0 atomic path ----------------
    char* p = (char*)d_ws;
    float2* Sv_pos = (float2*)p; p += (size_t)nv * sizeof(float2);
    float2* Sv_neg = (float2*)p; p += (size_t)nv * sizeof(float2);
    float2* Sc_pos = (float2*)p; p += (size_t)nc * sizeof(float2);
    float2* Sc_neg = (float2*)p; p += (size_t)nc * sizeof(float2);
    const size_t s_bytes = (size_t)(2 * nv + 2 * nc) * sizeof(float2);
    float2* xc2 = (float2*)p; p += (size_t)nc * sizeof(float2);
    float* inv_c = (float*)p; p += (size_t)nc * sizeof(float);
    float* inv_v = (float*)p; p += (size_t)nv * sizeof(float);
    float* cntc_pos = (float*)p; p += (size_t)nc * sizeof(float);
    float* cntc_neg = (float*)p; p += (size_t)nc * sizeof(float);
    float* cntv_pos = (float*)p; p += (size_t)nv * sizeof(float);
    float* cntv_neg = (float*)p; p += (size_t)nv * sizeof(float);
    const size_t cnt_bytes = (size_t)(2 * nc + 2 * nv) * sizeof(float);
    float2* xv = (float2*)d_out;

    hipMemsetAsync(Sv_pos, 0, s_bytes, stream);
    hipMemsetAsync(cntc_pos, 0, cnt_bytes, stream);
    init_nodes<<<cdiv_h(nc, B), B, 0, stream>>>(x_clause, deg_clause, W0c, b0c, xc2, inv_c, nc);
    init_nodes<<<cdiv_h(nv, B), B, 0, stream>>>(x_variable, deg_var, W0v, b0v, xv, inv_v, nv);
    count_edges<<<cdiv_h(e, B), B, 0, stream>>>(pos_src, pos_trg, cntc_pos, cntv_pos, e);
    count_edges<<<cdiv_h(e, B), B, 0, stream>>>(neg_src, neg_trg, cntc_neg, cntv_neg, e);
    for (int l = 0; l < 4; ++l) {
        edge_pass<<<cdiv_h(e, B), B, 0, stream>>>(pos_src, pos_trg, xc2, xv, inv_c, inv_v,
                                                  Sv_pos, Sc_pos, e);
        edge_pass<<<cdiv_h(e, B), B, 0, stream>>>(neg_src, neg_trg, xc2, xv, inv_c, inv_v,
                                                  Sv_neg, Sc_neg, e);
        node_update<<<cdiv_h(nv, B), B, 0, stream>>>(xv, Sv_pos, Sv_neg, inv_v,
                                                     cntv_pos, cntv_neg, Wv + l * 12, bv + l * 2, nv);
        node_update<<<cdiv_h(nc, B), B, 0, stream>>>(xc2, Sc_pos, Sc_neg, inv_c,
                                                     cntc_pos, cntc_neg, Wc + l * 12, bc + l * 2, nc);
        if (l < 3) hipMemsetAsync(Sv_pos, 0, s_bytes, stream);
    }
}

// Round 3
// 1954.303 us; speedup vs baseline: 5.4589x; 1.2424x over previous
//
#include <hip/hip_runtime.h>

// G4GCN: 4-layer linear bipartite GNN (clauses <-> variables), feature dim 2.
//
// Round-2 lesson: v_layer was gather-miss bound (1.25 GB FETCH = 20M 64B lines
// from xc 16MB + deg_c 8MB random gathers vs 4MB per-XCD L2).
// Round-3 design:
//  - y arrays: y = inv_sqrt_deg * x packed as bf16x2 (4B/node). One gather
//    array instead of two; yc = 8MB, yv = 2MB (L2-resident).
//  - v-views are built FROM the clause-bucketed views, so entries within each
//    v-bucket are clause-ascending (chunk granularity) -> every aggregation
//    block sweeps yc monotonically -> L2 behaves like a moving window.
//  - All aggregation in LDS (no global atomics). Counts recomputed in LDS
//    per layer (the "+x_trg" term telescopes to cnt*x).

#define GAB 256  // blocks for build passes (hist/scatter); rowscan width must match

static inline int cdiv_h(long long a, long long b) { return (int)((a + b - 1) / b); }

__device__ inline float bf_lo(unsigned u) { return __uint_as_float(u << 16); }
__device__ inline float bf_hi(unsigned u) { return __uint_as_float(u & 0xffff0000u); }
__device__ inline unsigned packy(float a, float b) {
    unsigned ua = __float_as_uint(a), ub = __float_as_uint(b);
    ua = (ua + 0x7fffu + ((ua >> 16) & 1u)) >> 16;
    ub = (ub + 0x7fffu + ((ub >> 16) & 1u)) & 0xffff0000u;
    return ua | ub;
}

// ---------------- build: counting partition ----------------

__global__ void hist_kernel(const int* __restrict__ key, int e, int chunk, int shift,
                            int nb, unsigned* __restrict__ hist /*[nb][GAB]*/) {
    extern __shared__ unsigned h[];
    int blk = blockIdx.x, tid = threadIdx.x;
    for (int i = tid; i < nb; i += blockDim.x) h[i] = 0u;
    __syncthreads();
    int s = blk * chunk, epos = min(e, s + chunk);
    for (int i = s + tid; i < epos; i += blockDim.x)
        atomicAdd(&h[key[i] >> shift], 1u);
    __syncthreads();
    for (int i = tid; i < nb; i += blockDim.x) hist[(size_t)i * GAB + blk] = h[i];
}

// one block (256 threads) per bucket row: exclusive scan of hist[b][0..GAB)
__global__ void rowscan256(const unsigned* __restrict__ hist, unsigned* __restrict__ rowscan,
                           unsigned* __restrict__ row_total) {
    __shared__ unsigned ts[256];
    int b = blockIdx.x, t = threadIdx.x;
    unsigned v0 = hist[(size_t)b * GAB + t];
    ts[t] = v0;
    __syncthreads();
    for (int off = 1; off < 256; off <<= 1) {
        unsigned v = (t >= off) ? ts[t - off] : 0u;
        __syncthreads();
        ts[t] += v;
        __syncthreads();
    }
    rowscan[(size_t)b * GAB + t] = ts[t] - v0;
    if (t == 255) row_total[b] = ts[255];
}

// single block, 1024 threads: exclusive scan of row_total[0..nb) -> base[0..nb]
__global__ void basescan_kernel(const unsigned* __restrict__ row_total,
                                unsigned* __restrict__ base, int nb) {
    __shared__ unsigned a[2048];
    __shared__ unsigned ts[1024];
    int t = threadIdx.x;
    a[t] = (t < nb) ? row_total[t] : 0u;
    a[t + 1024] = (t + 1024 < nb) ? row_total[t + 1024] : 0u;
    __syncthreads();
    unsigned a0 = a[2 * t], a1 = a[2 * t + 1];
    unsigned sum = a0 + a1;
    ts[t] = sum;
    __syncthreads();
    for (int off = 1; off < 1024; off <<= 1) {
        unsigned v = (t >= off) ? ts[t - off] : 0u;
        __syncthreads();
        ts[t] += v;
        __syncthreads();
    }
    unsigned b0 = ts[t] - sum;
    if (2 * t <= nb) base[2 * t] = b0;
    if (2 * t + 1 <= nb) base[2 * t + 1] = b0 + a0;
}

// original edge lists -> c-view: entry = (trg << shift) | (src & mask), bucketed by src
__global__ void scatter_kernel(const int* __restrict__ key, const int* __restrict__ payload,
                               int e, int chunk, int shift, int mask, int nb,
                               const unsigned* __restrict__ rowscan,
                               const unsigned* __restrict__ base,
                               unsigned* __restrict__ out) {
    extern __shared__ unsigned cur[];
    int blk = blockIdx.x, tid = threadIdx.x;
    for (int i = tid; i < nb; i += blockDim.x)
        cur[i] = base[i] + rowscan[(size_t)i * GAB + blk];
    __syncthreads();
    int s = blk * chunk, epos = min(e, s + chunk);
    for (int i = s + tid; i < epos; i += blockDim.x) {
        int k = key[i];
        int b = k >> shift;
        unsigned p = atomicAdd(&cur[b], 1u);
        out[p] = ((unsigned)payload[i] << shift) | (unsigned)(k & mask);
    }
}

// c-view (entries (v<<10|loc_c), c-bucket order) -> v-view: entry = (c<<8 | v&255),
// bucketed by v>>8. Reads are sequential; c recovered from position via base_c.
__global__ __launch_bounds__(256) void vscatter_kernel(
    const unsigned* __restrict__ cview, int e, int chunk, int nbc,
    const unsigned* __restrict__ base_c, const unsigned* __restrict__ rowscan_v,
    const unsigned* __restrict__ base_v, int nbv, unsigned* __restrict__ out) {
    extern __shared__ unsigned sm[];  // [nbv cursors][nbc+1 base_c]
    unsigned* cur = sm;
    unsigned* bc = sm + nbv;
    int blk = blockIdx.x, tid = threadIdx.x;
    for (int i = tid; i < nbv; i += 256)
        cur[i] = base_v[i] + rowscan_v[(size_t)i * GAB + blk];
    for (int i = tid; i <= nbc; i += 256) bc[i] = base_c[i];
    __syncthreads();
    int s = blk * chunk, epos = min(e, s + chunk);
    int i = s + tid;
    if (i < epos) {
        int lo = 0, hi = nbc;  // invariant: bc[lo] <= i < bc[hi]
        while (lo + 1 < hi) {
            int mid = (lo + hi) >> 1;
            if (bc[mid] <= (unsigned)i) lo = mid; else hi = mid;
        }
        int cb = lo;
        for (; i < epos; i += 256) {
            while ((unsigned)i >= bc[cb + 1]) ++cb;
            unsigned u = cview[i];
            unsigned v = u >> 10;
            unsigned c = ((unsigned)cb << 10) | (u & 1023u);
            unsigned p = atomicAdd(&cur[v >> 8], 1u);
            out[p] = (c << 8) | (v & 255u);
        }
    }
}

// ---------------- node init ----------------

__global__ void init_c_kernel(const float* __restrict__ x, const float* __restrict__ deg,
                              const float* __restrict__ W0, const float* __restrict__ b0,
                              float2* __restrict__ xc, unsigned* __restrict__ yc, int n) {
    int i = blockIdx.x * blockDim.x + threadIdx.x;
    if (i >= n) return;
    float xi = x[i];
    float2 o = make_float2(fmaf(xi, W0[0], b0[0]), fmaf(xi, W0[1], b0[1]));
    xc[i] = o;
    float d = deg[i];
    float inv = (d > 0.f) ? rsqrtf(d) : 0.f;
    yc[i] = packy(inv * o.x, inv * o.y);
}

__global__ void init_v_kernel(const float* __restrict__ x, const float* __restrict__ deg,
                              const float* __restrict__ W0, const float* __restrict__ b0,
                              float2* __restrict__ xv, unsigned* __restrict__ yv, int n) {
    int i = blockIdx.x * blockDim.x + threadIdx.x;
    if (i >= n) return;
    float xi = x[i];
    float2 o = make_float2(fmaf(xi, W0[0], b0[0]), fmaf(xi, W0[1], b0[1]));
    xv[i] = o;
    float d = deg[i];
    float inv = (d > 0.f) ? rsqrtf(d) : 0.f;
    yv[i] = packy(inv * o.x, inv * o.y);
}

// ---------------- per-layer fused kernels ----------------

// variable side: buckets of 256 nodes; gathers yc (bf16x2). writes xv_out (+ yv_out)
__global__ __launch_bounds__(256) void v_layer_kernel(
    const unsigned* __restrict__ bkt_pos, const unsigned* __restrict__ base_pos,
    const unsigned* __restrict__ bkt_neg, const unsigned* __restrict__ base_neg,
    const unsigned* __restrict__ yc, const float2* __restrict__ xv_in,
    const float* __restrict__ deg_v, const float* __restrict__ W,
    const float* __restrict__ bias, float2* __restrict__ xv_out,
    unsigned* __restrict__ yv_out, int nv, int writeY) {
    __shared__ float sx[2][256], sy[2][256], cnt[2][256];
    int b = blockIdx.x, t = threadIdx.x;
    sx[0][t] = 0.f; sx[1][t] = 0.f; sy[0][t] = 0.f; sy[1][t] = 0.f;
    cnt[0][t] = 0.f; cnt[1][t] = 0.f;
    __syncthreads();
    for (int pol = 0; pol < 2; ++pol) {
        const unsigned* bkt = pol ? bkt_neg : bkt_pos;
        const unsigned* bse = pol ? base_neg : base_pos;
        unsigned s = bse[b], epos = bse[b + 1];
        for (unsigned i = s + t; i < epos; i += 256) {
            unsigned u = bkt[i];
            unsigned c = u >> 8;
            int loc = (int)(u & 255u);
            unsigned yw = yc[c];
            atomicAdd(&sx[pol][loc], bf_lo(yw));
            atomicAdd(&sy[pol][loc], bf_hi(yw));
            atomicAdd(&cnt[pol][loc], 1.0f);
        }
    }
    __syncthreads();
    int node = b * 256 + t;
    if (node < nv) {
        float2 xi = xv_in[node];
        float dv = deg_v[node];
        float iv = (dv > 0.f) ? rsqrtf(dv) : 0.f;
        float m0 = fmaf(iv, sx[0][t], cnt[0][t] * xi.x);
        float m1 = fmaf(iv, sy[0][t], cnt[0][t] * xi.y);
        float m2 = fmaf(iv, sx[1][t], cnt[1][t] * xi.x);
        float m3 = fmaf(iv, sy[1][t], cnt[1][t] * xi.y);
        float o0 = bias[0] + m0 * W[0] + m1 * W[2] + m2 * W[4] + m3 * W[6] + xi.x * W[8] + xi.y * W[10];
        float o1 = bias[1] + m0 * W[1] + m1 * W[3] + m2 * W[5] + m3 * W[7] + xi.x * W[9] + xi.y * W[11];
        xv_out[node] = make_float2(o0, o1);
        if (writeY) yv_out[node] = packy(iv * o0, iv * o1);
    }
}

// clause side: buckets of 1024 nodes; gathers yv (bf16x2, L2-resident).
// xc updated in place; yc rewritten for next layer.
__global__ __launch_bounds__(256) void c_layer_kernel(
    const unsigned* __restrict__ bkt_pos, const unsigned* __restrict__ base_pos,
    const unsigned* __restrict__ bkt_neg, const unsigned* __restrict__ base_neg,
    const unsigned* __restrict__ yv, float2* __restrict__ xc,
    const float* __restrict__ deg_c, unsigned* __restrict__ yc,
    const float* __restrict__ W, const float* __restrict__ bias, int nc) {
    __shared__ float sx[2][1024], sy[2][1024], cnt[2][1024];
    int b = blockIdx.x, t = threadIdx.x;
    for (int k = 0; k < 4; ++k) {
        int j = t + 256 * k;
        sx[0][j] = 0.f; sx[1][j] = 0.f; sy[0][j] = 0.f; sy[1][j] = 0.f;
        cnt[0][j] = 0.f; cnt[1][j] = 0.f;
    }
    __syncthreads();
    for (int pol = 0; pol < 2; ++pol) {
        const unsigned* bkt = pol ? bkt_neg : bkt_pos;
        const unsigned* bse = pol ? base_neg : base_pos;
        unsigned s = bse[b], epos = bse[b + 1];
        for (unsigned i = s + t; i < epos; i += 256) {
            unsigned u = bkt[i];
            unsigned v = u >> 10;
            int loc = (int)(u & 1023u);
            unsigned yw = yv[v];
            atomicAdd(&sx[pol][loc], bf_lo(yw));
            atomicAdd(&sy[pol][loc], bf_hi(yw));
            atomicAdd(&cnt[pol][loc], 1.0f);
        }
    }
    __syncthreads();
    for (int k = 0; k < 4; ++k) {
        int j = t + 256 * k;
        int node = b * 1024 + j;
        if (node < nc) {
            float2 xi = xc[node];
            float dc = deg_c[node];
            float ic = (dc > 0.f) ? rsqrtf(dc) : 0.f;
            float m0 = fmaf(ic, sx[0][j], cnt[0][j] * xi.x);
            float m1 = fmaf(ic, sy[0][j], cnt[0][j] * xi.y);
            float m2 = fmaf(ic, sx[1][j], cnt[1][j] * xi.x);
            float m3 = fmaf(ic, sy[1][j], cnt[1][j] * xi.y);
            float o0 = bias[0] + m0 * W[0] + m1 * W[2] + m2 * W[4] + m3 * W[6] + xi.x * W[8] + xi.y * W[10];
            float o1 = bias[1] + m0 * W[1] + m1 * W[3] + m2 * W[5] + m3 * W[7] + xi.x * W[9] + xi.y * W[11];
            xc[node] = make_float2(o0, o1);
            yc[node] = packy(ic * o0, ic * o1);
        }
    }
}

// ---------------- fallback (atomic path, ~56MB ws) ----------------

__global__ void init_nodes(const float* __restrict__ x, const float* __restrict__ deg,
                           const float* __restrict__ W0, const float* __restrict__ b0,
                           float2* __restrict__ xf, float* __restrict__ inv, int n) {
    int i = blockIdx.x * blockDim.x + threadIdx.x;
    if (i >= n) return;
    float xi = x[i];
    xf[i] = make_float2(fmaf(xi, W0[0], b0[0]), fmaf(xi, W0[1], b0[1]));
    float d = deg[i];
    inv[i] = (d > 0.0f) ? (1.0f / sqrtf(d)) : 0.0f;
}

__global__ void count_edges(const int* __restrict__ src, const int* __restrict__ trg,
                            float* __restrict__ cnt_src, float* __restrict__ cnt_trg, int e) {
    int i = blockIdx.x * blockDim.x + threadIdx.x;
    if (i >= e) return;
    atomicAdd(&cnt_src[src[i]], 1.0f);
    atomicAdd(&cnt_trg[trg[i]], 1.0f);
}

__global__ void edge_pass(const int* __restrict__ src, const int* __restrict__ trg,
                          const float2* __restrict__ xc, const float2* __restrict__ xv,
                          const float* __restrict__ inv_c, const float* __restrict__ inv_v,
                          float2* __restrict__ Sv, float2* __restrict__ Sc, int e) {
    int i = blockIdx.x * blockDim.x + threadIdx.x;
    if (i >= e) return;
    int c = src[i];
    int v = trg[i];
    float ic = inv_c[c], iv = inv_v[v];
    float2 a = xc[c];
    float2 b = xv[v];
    atomicAdd(&Sv[v].x, a.x * ic);
    atomicAdd(&Sv[v].y, a.y * ic);
    atomicAdd(&Sc[c].x, b.x * iv);
    atomicAdd(&Sc[c].y, b.y * iv);
}

__global__ void node_update(float2* __restrict__ x, const float2* __restrict__ Sp,
                            const float2* __restrict__ Sn, const float* __restrict__ inv,
                            const float* __restrict__ cp, const float* __restrict__ cn,
                            const float* __restrict__ W, const float* __restrict__ b, int n) {
    int i = blockIdx.x * blockDim.x + threadIdx.x;
    if (i >= n) return;
    float2 xi = x[i];
    float ii = inv[i];
    float2 sp = Sp[i], sn = Sn[i];
    float cpi = cp[i], cni = cn[i];
    float m0 = fmaf(ii, sp.x, cpi * xi.x);
    float m1 = fmaf(ii, sp.y, cpi * xi.y);
    float m2 = fmaf(ii, sn.x, cni * xi.x);
    float m3 = fmaf(ii, sn.y, cni * xi.y);
    float o0 = b[0] + m0 * W[0] + m1 * W[2] + m2 * W[4] + m3 * W[6] + xi.x * W[8] + xi.y * W[10];
    float o1 = b[1] + m0 * W[1] + m1 * W[3] + m2 * W[5] + m3 * W[7] + xi.x * W[9] + xi.y * W[11];
    x[i] = make_float2(o0, o1);
}

// ---------------- launch ----------------

extern "C" void kernel_launch(void* const* d_in, const int* in_sizes, int n_in,
                              void* d_out, int out_size, void* d_ws, size_t ws_size,
                              hipStream_t stream) {
    const float* x_clause   = (const float*)d_in[0];
    const float* x_variable = (const float*)d_in[1];
    const float* deg_clause = (const float*)d_in[2];
    const float* deg_var    = (const float*)d_in[3];
    const int*   pos_src    = (const int*)d_in[4];
    const int*   pos_trg    = (const int*)d_in[5];
    const int*   neg_src    = (const int*)d_in[6];
    const int*   neg_trg    = (const int*)d_in[7];
    const float* W0c        = (const float*)d_in[8];
    const float* b0c        = (const float*)d_in[9];
    const float* W0v        = (const float*)d_in[10];
    const float* b0v        = (const float*)d_in[11];
    const float* Wc         = (const float*)d_in[12];
    const float* bc         = (const float*)d_in[13];
    const float* Wv         = (const float*)d_in[14];
    const float* bv         = (const float*)d_in[15];

    const int nc = in_sizes[0];
    const int nv = in_sizes[1];
    const int e  = in_sizes[4];
    const int B = 256;

    const int NBV = cdiv_h(nv, 256);
    const int NBC = cdiv_h(nc, 1024);
    const int maxnb = NBV > NBC ? NBV : NBC;

    size_t off = 0;
    auto alloc = [&](size_t bytes) {
        void* p = (char*)d_ws + off;
        off += (bytes + 255) & ~(size_t)255;
        return p;
    };
    unsigned* cview_p = (unsigned*)alloc((size_t)e * 4);
    unsigned* cview_n = (unsigned*)alloc((size_t)e * 4);
    unsigned* vview_p = (unsigned*)alloc((size_t)e * 4);
    unsigned* vview_n = (unsigned*)alloc((size_t)e * 4);
    unsigned* hist    = (unsigned*)alloc((size_t)maxnb * GAB * 4);
    unsigned* rowscan = (unsigned*)alloc((size_t)maxnb * GAB * 4);
    unsigned* row_tot = (unsigned*)alloc((size_t)maxnb * 4);
    unsigned* base_cp = (unsigned*)alloc((size_t)(NBC + 1) * 4);
    unsigned* base_cn = (unsigned*)alloc((size_t)(NBC + 1) * 4);
    unsigned* base_vp = (unsigned*)alloc((size_t)(NBV + 1) * 4);
    unsigned* base_vn = (unsigned*)alloc((size_t)(NBV + 1) * 4);
    float2*   xc      = (float2*)alloc((size_t)nc * 8);
    unsigned* yc      = (unsigned*)alloc((size_t)nc * 4);
    float2*   xvB     = (float2*)alloc((size_t)nv * 8);
    unsigned* yvA     = (unsigned*)alloc((size_t)nv * 4);
    unsigned* yvB     = (unsigned*)alloc((size_t)nv * 4);
    const size_t required = off;

    if (required <= ws_size && NBV <= 2048 && NBC <= 2048) {
        const int chunk = cdiv_h(e, GAB);
        struct { const int* key; const int* pay; unsigned* cv; unsigned* bcx; unsigned* vv; unsigned* bvx; } L[2] = {
            { pos_src, pos_trg, cview_p, base_cp, vview_p, base_vp },
            { neg_src, neg_trg, cview_n, base_cn, vview_n, base_vn },
        };
        for (int p = 0; p < 2; ++p) {
            // clause-bucketed view
            hist_kernel<<<GAB, B, (size_t)NBC * 4, stream>>>(L[p].key, e, chunk, 10, NBC, hist);
            rowscan256<<<NBC, B, 0, stream>>>(hist, rowscan, row_tot);
            basescan_kernel<<<1, 1024, 0, stream>>>(row_tot, L[p].bcx, NBC);
            scatter_kernel<<<GAB, B, (size_t)NBC * 4, stream>>>(L[p].key, L[p].pay, e, chunk,
                                                                10, 1023, NBC, rowscan, L[p].bcx, L[p].cv);
            // variable-bucketed view, built from the c-view (clause-ascending)
            hist_kernel<<<GAB, B, (size_t)NBV * 4, stream>>>((const int*)L[p].cv, e, chunk, 18, NBV, hist);
            rowscan256<<<NBV, B, 0, stream>>>(hist, rowscan, row_tot);
            basescan_kernel<<<1, 1024, 0, stream>>>(row_tot, L[p].bvx, NBV);
            vscatter_kernel<<<GAB, B, (size_t)(NBV + NBC + 1) * 4, stream>>>(
                L[p].cv, e, chunk, NBC, L[p].bcx, rowscan, L[p].bvx, NBV, L[p].vv);
        }

        float2* xvA = (float2*)d_out;  // A->B->A->B->A: final lands in d_out
        init_c_kernel<<<cdiv_h(nc, B), B, 0, stream>>>(x_clause, deg_clause, W0c, b0c, xc, yc, nc);
        init_v_kernel<<<cdiv_h(nv, B), B, 0, stream>>>(x_variable, deg_var, W0v, b0v, xvA, yvA, nv);

        float2* cur = xvA;  float2* nxt = xvB;
        unsigned* ycur = yvA; unsigned* ynxt = yvB;
        for (int l = 0; l < 4; ++l) {
            v_layer_kernel<<<NBV, B, 0, stream>>>(vview_p, base_vp, vview_n, base_vn,
                                                  yc, cur, deg_var, Wv + l * 12, bv + l * 2,
                                                  nxt, ynxt, nv, (l < 3) ? 1 : 0);
            if (l < 3) {
                c_layer_kernel<<<NBC, B, 0, stream>>>(cview_p, base_cp, cview_n, base_cn,
                                                      ycur, xc, deg_clause, yc,
                                                      Wc + l * 12, bc + l * 2, nc);
            }
            float2* tx = cur; cur = nxt; nxt = tx;
            unsigned* ty = ycur; ycur = ynxt; ynxt = ty;
        }
        return;
    }

    // ---------------- fallback: atomic path ----------------
    char* p = (char*)d_ws;
    float2* Sv_pos = (float2*)p; p += (size_t)nv * sizeof(float2);
    float2* Sv_neg = (float2*)p; p += (size_t)nv * sizeof(float2);
    float2* Sc_pos = (float2*)p; p += (size_t)nc * sizeof(float2);
    float2* Sc_neg = (float2*)p; p += (size_t)nc * sizeof(float2);
    const size_t s_bytes = (size_t)(2 * nv + 2 * nc) * sizeof(float2);
    float2* xc2 = (float2*)p; p += (size_t)nc * sizeof(float2);
    float* inv_c = (float*)p; p += (size_t)nc * sizeof(float);
    float* inv_v = (float*)p; p += (size_t)nv * sizeof(float);
    float* cntc_pos = (float*)p; p += (size_t)nc * sizeof(float);
    float* cntc_neg = (float*)p; p += (size_t)nc * sizeof(float);
    float* cntv_pos = (float*)p; p += (size_t)nv * sizeof(float);
    float* cntv_neg = (float*)p; p += (size_t)nv * sizeof(float);
    const size_t cnt_bytes = (size_t)(2 * nc + 2 * nv) * sizeof(float);
    float2* xv = (float2*)d_out;

    hipMemsetAsync(Sv_pos, 0, s_bytes, stream);
    hipMemsetAsync(cntc_pos, 0, cnt_bytes, stream);
    init_nodes<<<cdiv_h(nc, B), B, 0, stream>>>(x_clause, deg_clause, W0c, b0c, xc2, inv_c, nc);
    init_nodes<<<cdiv_h(nv, B), B, 0, stream>>>(x_variable, deg_var, W0v, b0v, xv, inv_v, nv);
    count_edges<<<cdiv_h(e, B), B, 0, stream>>>(pos_src, pos_trg, cntc_pos, cntv_pos, e);
    count_edges<<<cdiv_h(e, B), B, 0, stream>>>(neg_src, neg_trg, cntc_neg, cntv_neg, e);
    for (int l = 0; l < 4; ++l) {
        edge_pass<<<cdiv_h(e, B), B, 0, stream>>>(pos_src, pos_trg, xc2, xv, inv_c, inv_v,
                                                  Sv_pos, Sc_pos, e);
        edge_pass<<<cdiv_h(e, B), B, 0, stream>>>(neg_src, neg_trg, xc2, xv, inv_c, inv_v,
                                                  Sv_neg, Sc_neg, e);
        node_update<<<cdiv_h(nv, B), B, 0, stream>>>(xv, Sv_pos, Sv_neg, inv_v,
                                                     cntv_pos, cntv_neg, Wv + l * 12, bv + l * 2, nv);
        node_update<<<cdiv_h(nc, B), B, 0, stream>>>(xc2, Sc_pos, Sc_neg, inv_c,
                                                     cntc_pos, cntc_neg, Wc + l * 12, bc + l * 2, nc);
        if (l < 3) hipMemsetAsync(Sv_pos, 0, s_bytes, stream);
    }
}